// Round 1
// baseline (265.990 us; speedup 1.0000x reference)
//
#include <hip/hip_runtime.h>

#define LN_EPS 1e-5f

// ---------------------------------------------------------------------------
// Fused MLP: Y = relu? no -- Y = LN2( LN1( X @ W1 ) @ W2 ) with relu at end.
//   X: [M][K1], W1: [K1][128], W2: [128][128], Y: [M][128]
// Block: 512 threads, BM=64 rows. Thread (rg = t>>5 owns rows rg*4..+3,
// c = t&31 owns cols c*4..+3). 4x4 register micro-tile per thread.
// ---------------------------------------------------------------------------
template<int K1>
__global__ __launch_bounds__(512, 4)
void mlp_fused(const float* __restrict__ X,
               const float* __restrict__ W1,
               const float* __restrict__ g1v, const float* __restrict__ b1v,
               const float* __restrict__ W2,
               const float* __restrict__ g2v, const float* __restrict__ b2v,
               float* __restrict__ Y)
{
    __shared__ float sA[64][36];    // A tile 64x32, pad to 36 (144B rows, 16B-aligned cols)
    __shared__ float sB[32][128];   // W tile 32x128
    __shared__ float sY[64][132];   // post-LN1 activations (528B rows, 16B-aligned)

    const int t   = threadIdx.x;
    const int c   = t & 31;         // col group: cols c*4 .. c*4+3
    const int rg  = t >> 5;         // row group: rows rg*4 .. rg*4+3
    const int row0 = blockIdx.x * 64;

    float g1[4], b1[4], g2[4], b2[4];
    #pragma unroll
    for (int j = 0; j < 4; ++j) {
        g1[j] = g1v[c*4+j]; b1[j] = b1v[c*4+j];
        g2[j] = g2v[c*4+j]; b2[j] = b2v[c*4+j];
    }

    float acc[4][4];
    #pragma unroll
    for (int i = 0; i < 4; ++i)
        #pragma unroll
        for (int j = 0; j < 4; ++j) acc[i][j] = 0.0f;

    // ---------------- Phase 1: H1 = X @ W1 ----------------
    for (int k0 = 0; k0 < K1; k0 += 32) {
        {   // stage A: 64 rows x 32 k = 512 float4, one per thread
            int row = t >> 3;
            int kc  = (t & 7) * 4;
            float4 a = *(const float4*)&X[(row0 + row) * K1 + k0 + kc];
            *(float4*)&sA[row][kc] = a;
        }
        #pragma unroll
        for (int u = 0; u < 2; ++u) {  // stage B: 32x128 = 1024 float4
            int f4  = t + u * 512;
            int row = f4 >> 5;
            int col = (f4 & 31) * 4;
            *(float4*)&sB[row][col] = *(const float4*)&W1[(k0 + row) * 128 + col];
        }
        __syncthreads();
        #pragma unroll
        for (int kk = 0; kk < 32; ++kk) {
            float4 b = *(const float4*)&sB[kk][c*4];
            #pragma unroll
            for (int i = 0; i < 4; ++i) {
                float a = sA[rg*4+i][kk];
                acc[i][0] = fmaf(a, b.x, acc[i][0]);
                acc[i][1] = fmaf(a, b.y, acc[i][1]);
                acc[i][2] = fmaf(a, b.z, acc[i][2]);
                acc[i][3] = fmaf(a, b.w, acc[i][3]);
            }
        }
        __syncthreads();
    }

    // ---------------- Phase 2: LN1 -> sY ----------------
    #pragma unroll
    for (int i = 0; i < 4; ++i) {
        float s = acc[i][0] + acc[i][1] + acc[i][2] + acc[i][3];
        float q = acc[i][0]*acc[i][0] + acc[i][1]*acc[i][1]
                + acc[i][2]*acc[i][2] + acc[i][3]*acc[i][3];
        #pragma unroll
        for (int m = 16; m >= 1; m >>= 1) {
            s += __shfl_xor(s, m, 64);
            q += __shfl_xor(q, m, 64);
        }
        float mean = s * (1.0f / 128.0f);
        float var  = q * (1.0f / 128.0f) - mean * mean;
        float rstd = rsqrtf(var + LN_EPS);
        float4 y;
        y.x = (acc[i][0] - mean) * rstd * g1[0] + b1[0];
        y.y = (acc[i][1] - mean) * rstd * g1[1] + b1[1];
        y.z = (acc[i][2] - mean) * rstd * g1[2] + b1[2];
        y.w = (acc[i][3] - mean) * rstd * g1[3] + b1[3];
        *(float4*)&sY[rg*4+i][c*4] = y;
    }
    // (barrier for sY is the first __syncthreads in phase 3)

    // ---------------- Phase 3: H2 = Y1 @ W2 ----------------
    float acc2[4][4];
    #pragma unroll
    for (int i = 0; i < 4; ++i)
        #pragma unroll
        for (int j = 0; j < 4; ++j) acc2[i][j] = 0.0f;

    for (int k0 = 0; k0 < 128; k0 += 32) {
        #pragma unroll
        for (int u = 0; u < 2; ++u) {
            int f4  = t + u * 512;
            int row = f4 >> 5;
            int col = (f4 & 31) * 4;
            *(float4*)&sB[row][col] = *(const float4*)&W2[(k0 + row) * 128 + col];
        }
        __syncthreads();
        #pragma unroll
        for (int kk = 0; kk < 32; ++kk) {
            float4 b = *(const float4*)&sB[kk][c*4];
            #pragma unroll
            for (int i = 0; i < 4; ++i) {
                float a = sY[rg*4+i][k0 + kk];
                acc2[i][0] = fmaf(a, b.x, acc2[i][0]);
                acc2[i][1] = fmaf(a, b.y, acc2[i][1]);
                acc2[i][2] = fmaf(a, b.z, acc2[i][2]);
                acc2[i][3] = fmaf(a, b.w, acc2[i][3]);
            }
        }
        __syncthreads();
    }

    // ---------------- Phase 4: LN2 + ReLU -> Y ----------------
    #pragma unroll
    for (int i = 0; i < 4; ++i) {
        float s = acc2[i][0] + acc2[i][1] + acc2[i][2] + acc2[i][3];
        float q = acc2[i][0]*acc2[i][0] + acc2[i][1]*acc2[i][1]
                + acc2[i][2]*acc2[i][2] + acc2[i][3]*acc2[i][3];
        #pragma unroll
        for (int m = 16; m >= 1; m >>= 1) {
            s += __shfl_xor(s, m, 64);
            q += __shfl_xor(q, m, 64);
        }
        float mean = s * (1.0f / 128.0f);
        float var  = q * (1.0f / 128.0f) - mean * mean;
        float rstd = rsqrtf(var + LN_EPS);
        float4 y;
        y.x = fmaxf((acc2[i][0] - mean) * rstd * g2[0] + b2[0], 0.0f);
        y.y = fmaxf((acc2[i][1] - mean) * rstd * g2[1] + b2[1], 0.0f);
        y.z = fmaxf((acc2[i][2] - mean) * rstd * g2[2] + b2[2], 0.0f);
        y.w = fmaxf((acc2[i][3] - mean) * rstd * g2[3] + b2[3], 0.0f);
        *(float4*)&Y[(row0 + rg*4 + i) * 128 + c*4] = y;
    }
}

// ---------------------------------------------------------------------------
// Scatter, numpy semantics (last duplicate wins):
//   pass 1: winner[slot] = max over i of i       (slot = nr[i]*N + nc[i])
//   pass 2: slot with winner i>=0:  out[slot] = out[slot] + fc[i % (Lc*N)]
// ---------------------------------------------------------------------------
__global__ void winner_kernel(const int* __restrict__ nr,
                              const int* __restrict__ nc,
                              int* __restrict__ w, int n)
{
    int i = blockIdx.x * blockDim.x + threadIdx.x;
    if (i < n) {
        int slot = nr[i] * 32 + nc[i];
        atomicMax(&w[slot], i);
    }
}

__global__ void scatter_apply(const int* __restrict__ w,
                              const float* __restrict__ fc,
                              float* __restrict__ out)
{
    int gid   = blockIdx.x * blockDim.x + threadIdx.x;
    int slot  = gid >> 5;          // 131072 slots
    int lane4 = gid & 31;          // float4 index within 128-wide row
    int i = w[slot];
    if (i < 0) return;
    int src = i & 32767;           // i % (Lc*N), Lc*N = 32768
    float4 a = *(const float4*)&out[slot * 128 + lane4 * 4];
    float4 b = *(const float4*)&fc [src  * 128 + lane4 * 4];
    a.x += b.x; a.y += b.y; a.z += b.z; a.w += b.w;
    *(float4*)&out[slot * 128 + lane4 * 4] = a;
}

extern "C" void kernel_launch(void* const* d_in, const int* in_sizes, int n_in,
                              void* d_out, int out_size, void* d_ws, size_t ws_size,
                              hipStream_t stream)
{
    const float* fcoarse = (const float*)d_in[0];   // [1024*32][256]
    const float* ffine   = (const float*)d_in[1];   // [4096*32][128]
    const float* w1c = (const float*)d_in[2];
    const float* g1c = (const float*)d_in[3];
    const float* b1c = (const float*)d_in[4];
    const float* w2c = (const float*)d_in[5];
    const float* g2c = (const float*)d_in[6];
    const float* b2c = (const float*)d_in[7];
    const float* w1f = (const float*)d_in[8];
    const float* g1f = (const float*)d_in[9];
    const float* b1f = (const float*)d_in[10];
    const float* w2f = (const float*)d_in[11];
    const float* g2f = (const float*)d_in[12];
    const float* b2f = (const float*)d_in[13];
    const int* nrow  = (const int*)d_in[14];        // K*Lc*N = 262144
    const int* ncol  = (const int*)d_in[15];
    // d_in[16] = keep_idx (unused by reference)

    float* out = (float*)d_out;                     // ff: [4096*32][128]

    const int Mc = 1024 * 32;                       // 32768
    const int Mf = 4096 * 32;                       // 131072
    const int nIdx = 8 * 1024 * 32;                 // 262144

    float* fc     = (float*)d_ws;                   // Mc*128 f32 = 16 MB
    int*   winner = (int*)((char*)d_ws + (size_t)Mc * 128 * sizeof(float));

    // coarse MLP -> fc (workspace)
    mlp_fused<256><<<Mc / 64, 512, 0, stream>>>(fcoarse, w1c, g1c, b1c,
                                                w2c, g2c, b2c, fc);
    // fine MLP -> out (this rewrites ALL of d_out every call: replay-safe)
    mlp_fused<128><<<Mf / 64, 512, 0, stream>>>(ffine, w1f, g1f, b1f,
                                                w2f, g2f, b2f, out);

    // winner init to -1, then last-write-wins resolution
    hipMemsetAsync(winner, 0xFF, (size_t)Mf * sizeof(int), stream);
    winner_kernel<<<(nIdx + 255) / 256, 256, 0, stream>>>(nrow, ncol, winner, nIdx);

    // apply: out[slot] = ff_orig[slot] + fc[i % (Lc*N)] for winning i
    scatter_apply<<<(Mf * 32) / 256, 256, 0, stream>>>(winner, fc, out);
}

// Round 2
// 93.755 us; speedup vs baseline: 2.8371x; 2.8371x over previous
//
#include <hip/hip_runtime.h>
#include <hip/hip_bf16.h>

typedef __attribute__((ext_vector_type(8))) short s8v;   // 8 x bf16 fragment
typedef __attribute__((ext_vector_type(4))) float f4v;   // 4 x f32 accumulator

__device__ __forceinline__ short f2bf(float f) {
    __hip_bfloat16 h = __float2bfloat16(f);
    union { __hip_bfloat16 h; short s; } u{h};
    return u.s;
}
__device__ __forceinline__ float bf2f(unsigned short v) {
    union { unsigned u; float f; } x; x.u = ((unsigned)v) << 16; return x.f;
}

// ---------------------------------------------------------------------------
// Pack f32 weights [K][128] into bf16 B-fragment order for mfma_16x16x32_bf16:
//   frag f = ks*8+n; lane l holds W[ks*32+(l>>4)*8+e][n*16+(l&15)], e=0..7.
// One block (64 thr) per fragment.
// ---------------------------------------------------------------------------
__global__ void pack_all(const float* __restrict__ w1c, const float* __restrict__ w2c,
                         const float* __restrict__ w1f, const float* __restrict__ w2f,
                         short* __restrict__ p1c, short* __restrict__ p2c,
                         short* __restrict__ p1f, short* __restrict__ p2f)
{
    int b = blockIdx.x;
    const float* W; short* P; int f;
    if      (b < 64)  { W = w1c; P = p1c; f = b; }        // K=256: 64 frags
    else if (b < 96)  { W = w2c; P = p2c; f = b - 64; }   // K=128: 32 frags
    else if (b < 128) { W = w1f; P = p1f; f = b - 96; }
    else              { W = w2f; P = p2f; f = b - 128; }
    int l = threadIdx.x, g = l >> 4, c = l & 15;
    int ks = f >> 3, n = f & 7;
    s8v o;
    #pragma unroll
    for (int e = 0; e < 8; ++e)
        o[e] = f2bf(W[(ks*32 + g*8 + e) * 128 + n*16 + c]);
    *(s8v*)(P + ((f*64 + l) << 3)) = o;
}

// ---------------------------------------------------------------------------
// Fused MFMA MLP: out = relu(LN2(LN1(X@W1)@W2)) [+ fused scatter when FINE]
// 256 threads = 4 waves; 128 rows/block; wave owns 32 rows (2 stripes of 16).
// ---------------------------------------------------------------------------
template<int K1, bool FINE>
__global__ __launch_bounds__(256)
void mlp_mfma(const float* __restrict__ X,
              const short* __restrict__ Wp1,
              const float* __restrict__ g1v, const float* __restrict__ b1v,
              const short* __restrict__ Wp2,
              const float* __restrict__ g2v, const float* __restrict__ b2v,
              float* __restrict__ outF,            // FINE: f32 output
              unsigned short* __restrict__ outB,   // !FINE: bf16 fc output
              const int* __restrict__ winner,
              const unsigned short* __restrict__ fcB)
{
    __shared__ short H1L[4][32][136];   // per-wave 32x128 bf16, pitch 136 (16B-aligned rows)

    const int t = threadIdx.x;
    const int wave = t >> 6, lane = t & 63;
    const int g = lane >> 4, c = lane & 15;
    const int wrow = blockIdx.x * 128 + wave * 32;

    // ---------- Layer 1: H1 = X @ W1 ----------
    f4v acc[2][8];
    #pragma unroll
    for (int s = 0; s < 2; ++s)
        #pragma unroll
        for (int n = 0; n < 8; ++n) acc[s][n] = (f4v){0.f, 0.f, 0.f, 0.f};

    #pragma unroll
    for (int ks = 0; ks < K1/32; ++ks) {
        s8v bf[8];
        #pragma unroll
        for (int n = 0; n < 8; ++n)
            bf[n] = *(const s8v*)(Wp1 + (((ks*8 + n)*64 + lane) << 3));
        s8v af[2];
        #pragma unroll
        for (int s = 0; s < 2; ++s) {
            const float* p = X + (size_t)(wrow + s*16 + c) * K1 + ks*32 + g*8;
            float4 a0 = *(const float4*)p;
            float4 a1 = *(const float4*)(p + 4);
            s8v t8;
            t8[0] = f2bf(a0.x); t8[1] = f2bf(a0.y); t8[2] = f2bf(a0.z); t8[3] = f2bf(a0.w);
            t8[4] = f2bf(a1.x); t8[5] = f2bf(a1.y); t8[6] = f2bf(a1.z); t8[7] = f2bf(a1.w);
            af[s] = t8;
        }
        #pragma unroll
        for (int s = 0; s < 2; ++s)
            #pragma unroll
            for (int n = 0; n < 8; ++n)
                acc[s][n] = __builtin_amdgcn_mfma_f32_16x16x32_bf16(af[s], bf[n], acc[s][n], 0, 0, 0);
    }

    // ---------- LN1 (in-register, 16-lane groups) -> LDS bf16 (XOR swizzle) ----------
    {
        float G[8], B[8];
        #pragma unroll
        for (int n = 0; n < 8; ++n) { G[n] = g1v[n*16 + c]; B[n] = b1v[n*16 + c]; }
        #pragma unroll
        for (int s = 0; s < 2; ++s) {
            #pragma unroll
            for (int j = 0; j < 4; ++j) {
                float sm = 0.f, sq = 0.f;
                #pragma unroll
                for (int n = 0; n < 8; ++n) { float v = acc[s][n][j]; sm += v; sq += v*v; }
                #pragma unroll
                for (int m = 1; m < 16; m <<= 1) {
                    sm += __shfl_xor(sm, m, 64);
                    sq += __shfl_xor(sq, m, 64);
                }
                float mean = sm * (1.f/128.f);
                float rstd = rsqrtf(sq * (1.f/128.f) - mean*mean + 1e-5f);
                int row = s*16 + g*4 + j;
                #pragma unroll
                for (int n = 0; n < 8; ++n) {
                    float y = (acc[s][n][j] - mean) * rstd * G[n] + B[n];
                    H1L[wave][row][(n*16 + c) ^ (g << 3)] = f2bf(y);
                }
            }
        }
    }

    // ---------- Layer 2: H2 = H1 @ W2 (A-frags via swizzled ds_read_b128) ----------
    f4v acc2[2][8];
    #pragma unroll
    for (int s = 0; s < 2; ++s)
        #pragma unroll
        for (int n = 0; n < 8; ++n) acc2[s][n] = (f4v){0.f, 0.f, 0.f, 0.f};

    const int rg = (c >> 2) & 3;
    #pragma unroll
    for (int ks = 0; ks < 4; ++ks) {
        s8v bf[8];
        #pragma unroll
        for (int n = 0; n < 8; ++n)
            bf[n] = *(const s8v*)(Wp2 + (((ks*8 + n)*64 + lane) << 3));
        s8v af[2];
        #pragma unroll
        for (int s = 0; s < 2; ++s)
            af[s] = *(const s8v*)&H1L[wave][s*16 + c][(ks*32 + g*8) ^ (rg << 3)];
        #pragma unroll
        for (int s = 0; s < 2; ++s)
            #pragma unroll
            for (int n = 0; n < 8; ++n)
                acc2[s][n] = __builtin_amdgcn_mfma_f32_16x16x32_bf16(af[s], bf[n], acc2[s][n], 0, 0, 0);
    }

    // ---------- LN2 + ReLU (+ fused gather-add scatter for FINE) ----------
    {
        float G[8], B[8];
        #pragma unroll
        for (int n = 0; n < 8; ++n) { G[n] = g2v[n*16 + c]; B[n] = b2v[n*16 + c]; }
        #pragma unroll
        for (int s = 0; s < 2; ++s) {
            #pragma unroll
            for (int j = 0; j < 4; ++j) {
                float sm = 0.f, sq = 0.f;
                #pragma unroll
                for (int n = 0; n < 8; ++n) { float v = acc2[s][n][j]; sm += v; sq += v*v; }
                #pragma unroll
                for (int m = 1; m < 16; m <<= 1) {
                    sm += __shfl_xor(sm, m, 64);
                    sq += __shfl_xor(sq, m, 64);
                }
                float mean = sm * (1.f/128.f);
                float rstd = rsqrtf(sq * (1.f/128.f) - mean*mean + 1e-5f);
                int R = wrow + s*16 + g*4 + j;
                float y[8];
                #pragma unroll
                for (int n = 0; n < 8; ++n)
                    y[n] = fmaxf((acc2[s][n][j] - mean) * rstd * G[n] + B[n], 0.f);
                if constexpr (FINE) {
                    int w = winner[R];
                    if (w >= 0) {
                        int src = w & 32767;                       // i % (Lc*N)
                        const unsigned short* fp = fcB + (size_t)src * 128 + c;
                        #pragma unroll
                        for (int n = 0; n < 8; ++n) y[n] += bf2f(fp[n*16]);
                    }
                    float* op = outF + (size_t)R * 128 + c;
                    #pragma unroll
                    for (int n = 0; n < 8; ++n) op[n*16] = y[n];
                } else {
                    unsigned short* op = outB + (size_t)R * 128 + c;
                    #pragma unroll
                    for (int n = 0; n < 8; ++n) op[n*16] = (unsigned short)f2bf(y[n]);
                }
            }
        }
    }
}

// ---------------------------------------------------------------------------
// Last-write-wins resolution: winner[slot] = max index writing that slot.
// ---------------------------------------------------------------------------
__global__ void winner_kernel(const int* __restrict__ nr,
                              const int* __restrict__ nc,
                              int* __restrict__ w, int n)
{
    int i = blockIdx.x * blockDim.x + threadIdx.x;
    if (i < n) atomicMax(&w[nr[i] * 32 + nc[i]], i);
}

extern "C" void kernel_launch(void* const* d_in, const int* in_sizes, int n_in,
                              void* d_out, int out_size, void* d_ws, size_t ws_size,
                              hipStream_t stream)
{
    const float* fcoarse = (const float*)d_in[0];
    const float* ffine   = (const float*)d_in[1];
    const float* w1c = (const float*)d_in[2];
    const float* g1c = (const float*)d_in[3];
    const float* b1c = (const float*)d_in[4];
    const float* w2c = (const float*)d_in[5];
    const float* g2c = (const float*)d_in[6];
    const float* b2c = (const float*)d_in[7];
    const float* w1f = (const float*)d_in[8];
    const float* g1f = (const float*)d_in[9];
    const float* b1f = (const float*)d_in[10];
    const float* w2f = (const float*)d_in[11];
    const float* g2f = (const float*)d_in[12];
    const float* b2f = (const float*)d_in[13];
    const int* nrow  = (const int*)d_in[14];
    const int* ncol  = (const int*)d_in[15];

    float* out = (float*)d_out;

    const int Mc = 32768, Mf = 131072, nIdx = 262144;

    // workspace: fcB (bf16, 8MB) | winner (512KB) | packed weights (160KB)
    unsigned short* fcB = (unsigned short*)d_ws;
    char* base = (char*)d_ws;
    int*   winner = (int*)(base + 8u*1024*1024);
    short* p1c = (short*)(base + 8u*1024*1024 + 512u*1024);
    short* p2c = p1c + 256*128;
    short* p1f = p2c + 128*128;
    short* p2f = p1f + 128*128;

    pack_all<<<160, 64, 0, stream>>>(w1c, w2c, w1f, w2f, p1c, p2c, p1f, p2f);

    hipMemsetAsync(winner, 0xFF, (size_t)Mf * sizeof(int), stream);
    winner_kernel<<<(nIdx + 255)/256, 256, 0, stream>>>(nrow, ncol, winner, nIdx);

    // coarse MLP -> fcB (bf16)
    mlp_mfma<256, false><<<Mc/128, 256, 0, stream>>>(fcoarse, p1c, g1c, b1c,
                                                     p2c, g2c, b2c,
                                                     nullptr, fcB, nullptr, nullptr);
    // fine MLP + fused scatter -> out
    mlp_mfma<128, true><<<Mf/128, 256, 0, stream>>>(ffine, p1f, g1f, b1f,
                                                    p2f, g2f, b2f,
                                                    out, nullptr, winner, fcB);
}

// Round 3
// 86.399 us; speedup vs baseline: 3.0786x; 1.0851x over previous
//
#include <hip/hip_runtime.h>
#include <hip/hip_bf16.h>

typedef __attribute__((ext_vector_type(8))) short s8v;   // 8 x bf16 fragment
typedef __attribute__((ext_vector_type(4))) float f4v;   // 4 x f32 accumulator

__device__ __forceinline__ short f2bf(float f) {
    __hip_bfloat16 h = __float2bfloat16(f);
    union { __hip_bfloat16 h; short s; } u{h};
    return u.s;
}
__device__ __forceinline__ float bf2f(unsigned short v) {
    union { unsigned u; float f; } x; x.u = ((unsigned)v) << 16; return x.f;
}

// ---------------------------------------------------------------------------
// prep kernel: blocks [0,1024) do winner atomicMax; blocks [1024,1064) pack
// the four weight matrices into bf16 B-fragment order for mfma_16x16x32_bf16:
//   frag f = ks*8+n; lane l holds W[ks*32+(l>>4)*8+e][n*16+(l&15)], e=0..7.
// ---------------------------------------------------------------------------
__global__ void prep_kernel(const int* __restrict__ nr, const int* __restrict__ nc,
                            int* __restrict__ win,
                            const float* __restrict__ w1c, const float* __restrict__ w2c,
                            const float* __restrict__ w1f, const float* __restrict__ w2f,
                            short* __restrict__ p1c, short* __restrict__ p2c,
                            short* __restrict__ p1f, short* __restrict__ p2f)
{
    int b = blockIdx.x, t = threadIdx.x;
    if (b < 1024) {                       // winner: 1024*256 = 262144 indices
        int i = b * 256 + t;
        atomicMax(&win[nr[i] * 32 + nc[i]], i);
        return;
    }
    int id = (b - 1024) * 256 + t;        // 40*256 = 10240 = 160 frags * 64 lanes
    int f  = id >> 6, l = id & 63;
    const float* W; short* P; int fl;
    if      (f < 64)  { W = w1c; P = p1c; fl = f; }        // K=256: 64 frags
    else if (f < 96)  { W = w2c; P = p2c; fl = f - 64; }   // K=128: 32 frags
    else if (f < 128) { W = w1f; P = p1f; fl = f - 96; }
    else              { W = w2f; P = p2f; fl = f - 128; }
    int g = l >> 4, c = l & 15;
    int ks = fl >> 3, n = fl & 7;
    s8v o;
    #pragma unroll
    for (int e = 0; e < 8; ++e)
        o[e] = f2bf(W[(ks*32 + g*8 + e) * 128 + n*16 + c]);
    *(s8v*)(P + ((fl*64 + l) << 3)) = o;
}

// ---------------------------------------------------------------------------
// Fused MFMA MLP: out = relu(LN2(LN1(X@W1)@W2)) [+ fused scatter when FINE]
// 256 threads = 4 waves; 64 rows/block; each wave owns 16 rows.
// ---------------------------------------------------------------------------
template<int K1, bool FINE>
__global__ __launch_bounds__(256, 4)
void mlp_mfma(const float* __restrict__ X,
              const short* __restrict__ Wp1,
              const float* __restrict__ g1v, const float* __restrict__ b1v,
              const short* __restrict__ Wp2,
              const float* __restrict__ g2v, const float* __restrict__ b2v,
              float* __restrict__ outF,            // FINE: f32 output
              unsigned short* __restrict__ outB,   // !FINE: bf16 fc output
              const int* __restrict__ winner,
              const unsigned short* __restrict__ fcB)
{
    __shared__ short H1L[4][16][136];   // per-wave 16x128 bf16, pitch 136 shorts

    const int t = threadIdx.x;
    const int wave = t >> 6, lane = t & 63;
    const int g = lane >> 4, c = lane & 15;
    const int wrow = blockIdx.x * 64 + wave * 16;

    // ---------- Layer 1: H1 = X @ W1 ----------
    f4v acc[8];
    #pragma unroll
    for (int n = 0; n < 8; ++n) acc[n] = (f4v){0.f, 0.f, 0.f, 0.f};

    #pragma unroll
    for (int ks = 0; ks < K1/32; ++ks) {
        s8v af;
        {
            const float* p = X + (size_t)(wrow + c) * K1 + ks*32 + g*8;
            float4 a0 = *(const float4*)p;
            float4 a1 = *(const float4*)(p + 4);
            af[0] = f2bf(a0.x); af[1] = f2bf(a0.y); af[2] = f2bf(a0.z); af[3] = f2bf(a0.w);
            af[4] = f2bf(a1.x); af[5] = f2bf(a1.y); af[6] = f2bf(a1.z); af[7] = f2bf(a1.w);
        }
        #pragma unroll
        for (int n = 0; n < 8; ++n) {
            s8v bf = *(const s8v*)(Wp1 + (((ks*8 + n)*64 + lane) << 3));
            acc[n] = __builtin_amdgcn_mfma_f32_16x16x32_bf16(af, bf, acc[n], 0, 0, 0);
        }
    }

    // ---------- LN1 (in-register, 16-lane groups) -> LDS bf16 (XOR swizzle) ----------
    {
        float G[8], B[8];
        #pragma unroll
        for (int n = 0; n < 8; ++n) { G[n] = g1v[n*16 + c]; B[n] = b1v[n*16 + c]; }
        #pragma unroll
        for (int j = 0; j < 4; ++j) {
            float sm = 0.f, sq = 0.f;
            #pragma unroll
            for (int n = 0; n < 8; ++n) { float v = acc[n][j]; sm += v; sq += v*v; }
            #pragma unroll
            for (int m = 1; m < 16; m <<= 1) {
                sm += __shfl_xor(sm, m, 64);
                sq += __shfl_xor(sq, m, 64);
            }
            float mean = sm * (1.f/128.f);
            float rstd = rsqrtf(sq * (1.f/128.f) - mean*mean + 1e-5f);
            int row = g*4 + j;
            #pragma unroll
            for (int n = 0; n < 8; ++n) {
                float y = (acc[n][j] - mean) * rstd * G[n] + B[n];
                H1L[wave][row][(n*16 + c) ^ (g << 3)] = f2bf(y);
            }
        }
    }

    // ---------- Layer 2: H2 = H1 @ W2 (A-frags via swizzled ds_read_b128) ----------
    f4v acc2[8];
    #pragma unroll
    for (int n = 0; n < 8; ++n) acc2[n] = (f4v){0.f, 0.f, 0.f, 0.f};

    const int rg = (c >> 2) & 3;
    #pragma unroll
    for (int ks = 0; ks < 4; ++ks) {
        s8v af = *(const s8v*)&H1L[wave][c][(ks*32 + g*8) ^ (rg << 3)];
        #pragma unroll
        for (int n = 0; n < 8; ++n) {
            s8v bf = *(const s8v*)(Wp2 + (((ks*8 + n)*64 + lane) << 3));
            acc2[n] = __builtin_amdgcn_mfma_f32_16x16x32_bf16(af, bf, acc2[n], 0, 0, 0);
        }
    }

    // ---------- LN2 + ReLU (+ fused gather-add scatter for FINE) ----------
    {
        float G[8], B[8];
        #pragma unroll
        for (int n = 0; n < 8; ++n) { G[n] = g2v[n*16 + c]; B[n] = b2v[n*16 + c]; }
        #pragma unroll
        for (int j = 0; j < 4; ++j) {
            float sm = 0.f, sq = 0.f;
            #pragma unroll
            for (int n = 0; n < 8; ++n) { float v = acc2[n][j]; sm += v; sq += v*v; }
            #pragma unroll
            for (int m = 1; m < 16; m <<= 1) {
                sm += __shfl_xor(sm, m, 64);
                sq += __shfl_xor(sq, m, 64);
            }
            float mean = sm * (1.f/128.f);
            float rstd = rsqrtf(sq * (1.f/128.f) - mean*mean + 1e-5f);
            int R = wrow + g*4 + j;
            float y[8];
            #pragma unroll
            for (int n = 0; n < 8; ++n)
                y[n] = fmaxf((acc2[n][j] - mean) * rstd * G[n] + B[n], 0.f);
            if constexpr (FINE) {
                int w = winner[R];
                if (w >= 0) {
                    int src = w & 32767;                       // i % (Lc*N)
                    const unsigned short* fp = fcB + (size_t)src * 128 + c;
                    #pragma unroll
                    for (int n = 0; n < 8; ++n) y[n] += bf2f(fp[n*16]);
                }
                float* op = outF + (size_t)R * 128 + c;
                #pragma unroll
                for (int n = 0; n < 8; ++n) op[n*16] = y[n];
            } else {
                unsigned short* op = outB + (size_t)R * 128 + c;
                #pragma unroll
                for (int n = 0; n < 8; ++n) op[n*16] = (unsigned short)f2bf(y[n]);
            }
        }
    }
}

extern "C" void kernel_launch(void* const* d_in, const int* in_sizes, int n_in,
                              void* d_out, int out_size, void* d_ws, size_t ws_size,
                              hipStream_t stream)
{
    const float* fcoarse = (const float*)d_in[0];
    const float* ffine   = (const float*)d_in[1];
    const float* w1c = (const float*)d_in[2];
    const float* g1c = (const float*)d_in[3];
    const float* b1c = (const float*)d_in[4];
    const float* w2c = (const float*)d_in[5];
    const float* g2c = (const float*)d_in[6];
    const float* b2c = (const float*)d_in[7];
    const float* w1f = (const float*)d_in[8];
    const float* g1f = (const float*)d_in[9];
    const float* b1f = (const float*)d_in[10];
    const float* w2f = (const float*)d_in[11];
    const float* g2f = (const float*)d_in[12];
    const float* b2f = (const float*)d_in[13];
    const int* nrow  = (const int*)d_in[14];
    const int* ncol  = (const int*)d_in[15];

    float* out = (float*)d_out;

    const int Mc = 32768, Mf = 131072;

    // workspace: fcB (bf16, 8MB) | winner (512KB) | packed weights (160KB)
    unsigned short* fcB = (unsigned short*)d_ws;
    char* base = (char*)d_ws;
    int*   winner = (int*)(base + 8u*1024*1024);
    short* p1c = (short*)(base + 8u*1024*1024 + 512u*1024);
    short* p2c = p1c + 256*128;
    short* p1f = p2c + 128*128;
    short* p2f = p1f + 128*128;

    hipMemsetAsync(winner, 0xFF, (size_t)Mf * sizeof(int), stream);
    // winner resolution (1024 blocks) + weight packing (40 blocks)
    prep_kernel<<<1064, 256, 0, stream>>>(nrow, ncol, winner,
                                          w1c, w2c, w1f, w2f,
                                          p1c, p2c, p1f, p2f);

    // coarse MLP -> fcB (bf16)
    mlp_mfma<256, false><<<Mc/64, 256, 0, stream>>>(fcoarse, p1c, g1c, b1c,
                                                    p2c, g2c, b2c,
                                                    nullptr, fcB, nullptr, nullptr);
    // fine MLP + fused scatter -> out
    mlp_mfma<128, true><<<Mf/64, 256, 0, stream>>>(ffine, p1f, g1f, b1f,
                                                   p2f, g2f, b2f,
                                                   out, nullptr, winner, fcB);
}